// Round 3
// baseline (10730.475 us; speedup 1.0000x reference)
//
#include <hip/hip_runtime.h>
#include <hip/hip_bf16.h>

using bf16 = __hip_bfloat16;
typedef __attribute__((ext_vector_type(8))) short s16x8;   // 8 bf16 = 4 VGPRs (MFMA frag)
typedef __attribute__((ext_vector_type(4))) float f32x4;

#define LN_EPS 1e-5f

__device__ inline unsigned short f2b(float x) {
    bf16 b = __float2bfloat16(x);
    return *reinterpret_cast<unsigned short*>(&b);
}
__device__ inline float b2f(unsigned short u) {
    return __bfloat162float(*reinterpret_cast<bf16*>(&u));
}

// split 8 fp32 into hi/lo bf16 chunks (16B each): x = hi + lo + O(2^-18 x)
__device__ inline void split8(const float* f, uint4& hi, uint4& lo) {
    union { uint4 v; unsigned short s[8]; } H, L;
    #pragma unroll
    for (int j = 0; j < 8; ++j) {
        float x = f[j];
        unsigned short h = f2b(x);
        H.s[j] = h;
        L.s[j] = f2b(x - b2f(h));
    }
    hi = H.v; lo = L.v;
}

// ---------------------------------------------------------------------------
// Split-precision GEMM: C[M,N] (fp32) = A[M,K] (fp32) * B^T  [+ fp32 bias]
//   B pre-split into (Bh, Bl) bf16, N x K row-major.  A split during staging.
//   acc += Ah*Bh + Al*Bh + Ah*Bl   (error ~2^-18, fp32-grade)
// tiles 128x128, BK=64, 256 threads (4 waves, each 64x64 = 4x4 frags 16x16x32)
// LDS XOR-swizzle: 16B chunk slot = chunk ^ (row & 7)  (involution, both sides)
// blockIdx.z selects one of two independent (A,B,C) sets.
// ---------------------------------------------------------------------------
__global__ __launch_bounds__(256) void gemm3(
    const float* __restrict__ A0, int lda0,
    const bf16* __restrict__ Bh0, const bf16* __restrict__ Bl0, int ldb0, int K0,
    const float* __restrict__ bias0, float* __restrict__ C0, int ldc0,
    const float* __restrict__ A1, int lda1,
    const bf16* __restrict__ Bh1, const bf16* __restrict__ Bl1, int ldb1, int K1,
    const float* __restrict__ bias1, float* __restrict__ C1, int ldc1)
{
    const float *A, *bias; const bf16 *Bh, *Bl; float* C; int lda, ldb, K, ldc;
    if (blockIdx.z == 0) { A=A0; Bh=Bh0; Bl=Bl0; bias=bias0; C=C0; lda=lda0; ldb=ldb0; K=K0; ldc=ldc0; }
    else                 { A=A1; Bh=Bh1; Bl=Bl1; bias=bias1; C=C1; lda=lda1; ldb=ldb1; K=K1; ldc=ldc1; }

    __shared__ __align__(16) unsigned char sAh[128*64*2];
    __shared__ __align__(16) unsigned char sAl[128*64*2];
    __shared__ __align__(16) unsigned char sBh[128*64*2];
    __shared__ __align__(16) unsigned char sBl[128*64*2];

    const int t  = threadIdx.x;
    const int l  = t & 63;
    const int w  = t >> 6;
    const int wr = (w >> 1) * 64;     // wave row base within tile
    const int wc = (w & 1)  * 64;     // wave col base within tile
    const int rowbase = blockIdx.x * 128;
    const int colbase = blockIdx.y * 128;

    f32x4 acc[4][4];
    #pragma unroll
    for (int m = 0; m < 4; ++m)
        #pragma unroll
        for (int n = 0; n < 4; ++n) acc[m][n] = (f32x4)(0.f);

    const int nkt = K >> 6;
    uint4 rah[4], ral[4], rbh[4], rbl[4];

    // staging slot s = t + i*256 : row = s>>3, cslot = s&7, holds chunk cslot^(row&7)
    #pragma unroll
    for (int i = 0; i < 4; ++i) {
        int s = t + i*256, row = s >> 3, c = (s & 7) ^ (row & 7);
        split8(A + (size_t)(rowbase+row)*lda + c*8, rah[i], ral[i]);
        rbh[i] = *(const uint4*)(Bh + (size_t)(colbase+row)*ldb + c*8);
        rbl[i] = *(const uint4*)(Bl + (size_t)(colbase+row)*ldb + c*8);
    }

    for (int kt = 0; kt < nkt; ++kt) {
        __syncthreads();                       // prior compute done reading LDS
        #pragma unroll
        for (int i = 0; i < 4; ++i) {
            int s = t + i*256;
            *(uint4*)(&sAh[s*16]) = rah[i];
            *(uint4*)(&sAl[s*16]) = ral[i];
            *(uint4*)(&sBh[s*16]) = rbh[i];
            *(uint4*)(&sBl[s*16]) = rbl[i];
        }
        if (kt + 1 < nkt) {                    // prefetch next K-tile (overlaps compute)
            int ko = (kt + 1) * 64;
            #pragma unroll
            for (int i = 0; i < 4; ++i) {
                int s = t + i*256, row = s >> 3, c = (s & 7) ^ (row & 7);
                split8(A + (size_t)(rowbase+row)*lda + ko + c*8, rah[i], ral[i]);
                rbh[i] = *(const uint4*)(Bh + (size_t)(colbase+row)*ldb + ko + c*8);
                rbl[i] = *(const uint4*)(Bl + (size_t)(colbase+row)*ldb + ko + c*8);
            }
        }
        __syncthreads();                       // ds_writes visible
        #pragma unroll
        for (int kk = 0; kk < 2; ++kk) {
            s16x8 bh[4], bl[4];
            #pragma unroll
            for (int n = 0; n < 4; ++n) {
                int rowb  = wc + n*16 + (l & 15);
                int chunk = kk*4 + (l >> 4);
                int boff  = rowb*128 + ((chunk ^ (rowb & 7)) << 4);
                bh[n] = *(const s16x8*)(&sBh[boff]);
                bl[n] = *(const s16x8*)(&sBl[boff]);
            }
            #pragma unroll
            for (int m = 0; m < 4; ++m) {
                int rowa  = wr + m*16 + (l & 15);
                int chunk = kk*4 + (l >> 4);
                int aoff  = rowa*128 + ((chunk ^ (rowa & 7)) << 4);
                s16x8 ah = *(const s16x8*)(&sAh[aoff]);
                s16x8 al = *(const s16x8*)(&sAl[aoff]);
                #pragma unroll
                for (int n = 0; n < 4; ++n) {
                    acc[m][n] = __builtin_amdgcn_mfma_f32_16x16x32_bf16(ah, bh[n], acc[m][n], 0, 0, 0);
                    acc[m][n] = __builtin_amdgcn_mfma_f32_16x16x32_bf16(al, bh[n], acc[m][n], 0, 0, 0);
                    acc[m][n] = __builtin_amdgcn_mfma_f32_16x16x32_bf16(ah, bl[n], acc[m][n], 0, 0, 0);
                }
            }
        }
    }

    // epilogue: C/D layout col = lane&15, row = (lane>>4)*4 + reg  [m89/m91]
    #pragma unroll
    for (int m = 0; m < 4; ++m) {
        int row0 = rowbase + wr + m*16 + (l >> 4)*4;
        #pragma unroll
        for (int n = 0; n < 4; ++n) {
            int col = colbase + wc + n*16 + (l & 15);
            float bv = bias ? bias[col] : 0.f;
            #pragma unroll
            for (int r = 0; r < 4; ++r)
                C[(size_t)(row0+r)*ldc + col] = acc[m][n][r] + bv;
        }
    }
}

// ---------------------------------------------------------------------------
// LN-LSTM cell pointwise: pre = preA + preB + b ; gates i,f,o,ct ;
// c = LayerNorm(f*c + i*ct) ; h = o * tanh(c).  One block (256 thr) per row.
// ---------------------------------------------------------------------------
__device__ inline float block_sum(float v, float* sred) {
    #pragma unroll
    for (int off = 32; off; off >>= 1) v += __shfl_down(v, off, 64);
    __syncthreads();                          // protect sred across calls
    if ((threadIdx.x & 63) == 0) sred[threadIdx.x >> 6] = v;
    __syncthreads();
    return sred[0] + sred[1] + sred[2] + sred[3];
}

__global__ __launch_bounds__(256) void lstm_cell(
    const float* __restrict__ preA, const float* __restrict__ preB,
    const float* __restrict__ bias,           // (4,1024) gate-major, fp32
    float* __restrict__ c_state, float* __restrict__ h_state)
{
    __shared__ float sred[4];
    const int b = blockIdx.x, t = threadIdx.x;
    float cn[4], og[4];
    float s = 0.f;
    #pragma unroll
    for (int j = 0; j < 4; ++j) {
        int h = t + j*256;
        size_t p = (size_t)b*4096 + h;
        float pi = preA[p]        + preB[p]        + bias[h];
        float pf = preA[p + 1024] + preB[p + 1024] + bias[h + 1024];
        float po = preA[p + 2048] + preB[p + 2048] + bias[h + 2048];
        float pc = preA[p + 3072] + preB[p + 3072] + bias[h + 3072];
        float ig = 1.f / (1.f + expf(-pi));
        float fg = 1.f / (1.f + expf(-pf));
        og[j]    = 1.f / (1.f + expf(-po));
        float ct = tanhf(pc);
        float v  = fg * c_state[(size_t)b*1024 + h] + ig * ct;
        cn[j] = v; s += v;
    }
    float mu  = block_sum(s, sred) * (1.f/1024.f);
    float vs = 0.f;
    #pragma unroll
    for (int j = 0; j < 4; ++j) { float d = cn[j] - mu; vs += d*d; }
    float var = block_sum(vs, sred) * (1.f/1024.f);
    float rs  = rsqrtf(var + LN_EPS);
    #pragma unroll
    for (int j = 0; j < 4; ++j) {
        int h = t + j*256;
        float cv = (cn[j] - mu) * rs;
        c_state[(size_t)b*1024 + h] = cv;
        h_state[(size_t)b*1024 + h] = og[j] * tanhf(cv);
    }
}

// ---------------------------------------------------------------------------
// One-time transpose+split wh[g] (K x N, fp32) -> wh_t hi/lo (N x K, bf16).
// grid (16,16,8): z<4 -> wh1 gate z ; z>=4 -> wh2 gate z-4. 64x64 LDS tiles.
// ---------------------------------------------------------------------------
__global__ __launch_bounds__(256) void transpose_wh_split(
    const float* __restrict__ wh1, const float* __restrict__ wh2,
    bf16* __restrict__ o1h, bf16* __restrict__ o1l,
    bf16* __restrict__ o2h, bf16* __restrict__ o2l)
{
    __shared__ float tile[64][65];
    const int z = blockIdx.z;
    const float* src = (z < 4 ? wh1 : wh2) + (size_t)(z & 3) * 1024 * 1024;
    bf16* dsth = (z < 4 ? o1h : o2h) + (size_t)(z & 3) * 1024 * 1024;
    bf16* dstl = (z < 4 ? o1l : o2l) + (size_t)(z & 3) * 1024 * 1024;
    const int kb = blockIdx.x * 64, nb = blockIdx.y * 64;
    const int t = threadIdx.x;
    #pragma unroll
    for (int i = 0; i < 16; ++i) {
        int idx = t + i*256, r = idx >> 6, c = idx & 63;
        tile[r][c] = src[(size_t)(kb + r)*1024 + nb + c];
    }
    __syncthreads();
    #pragma unroll
    for (int i = 0; i < 16; ++i) {
        int idx = t + i*256, r = idx >> 6, c = idx & 63;
        float x = tile[c][r];
        unsigned short h = f2b(x);
        dsth[(size_t)(nb + r)*1024 + kb + c] = *reinterpret_cast<bf16*>(&h);
        unsigned short lo = f2b(x - b2f(h));
        dstl[(size_t)(nb + r)*1024 + kb + c] = *reinterpret_cast<bf16*>(&lo);
    }
}

// fp32 -> hi/lo bf16 bulk split, 8 elems/thread
__global__ __launch_bounds__(256) void convert_split(
    const float* __restrict__ in, bf16* __restrict__ oh, bf16* __restrict__ ol, int n8)
{
    int i = blockIdx.x * 256 + threadIdx.x;
    if (i >= n8) return;
    float f[8];
    *(float4*)&f[0] = ((const float4*)in)[2*i];
    *(float4*)&f[4] = ((const float4*)in)[2*i + 1];
    uint4 hi, lo;
    split8(f, hi, lo);
    ((uint4*)oh)[i] = hi;
    ((uint4*)ol)[i] = lo;
}

// ---------------------------------------------------------------------------
// Final packing: d_out = [logit (fp32, written by fc2 gemm) | h0 | h1 | c0 | c1]
// ---------------------------------------------------------------------------
__global__ __launch_bounds__(256) void pack_out(
    const float* __restrict__ h0, const float* __restrict__ h1,
    const float* __restrict__ c0, const float* __restrict__ c1, float* __restrict__ out)
{
    const int NSZ = 512 * 1024;
    int i = blockIdx.x * 256 + threadIdx.x;
    out[NSZ     + i] = h0[i];
    out[2*NSZ   + i] = h1[i];
    out[3*NSZ   + i] = c0[i];
    out[4*NSZ   + i] = c1[i];
}

extern "C" void kernel_launch(void* const* d_in, const int* in_sizes, int n_in,
                              void* d_out, int out_size, void* d_ws, size_t ws_size,
                              hipStream_t stream)
{
    const float* obs   = (const float*)d_in[0];
    const float* fc1_w = (const float*)d_in[1];
    const float* fc1_b = (const float*)d_in[2];
    const float* wx1   = (const float*)d_in[3];
    const float* wh1   = (const float*)d_in[4];
    const float* b1    = (const float*)d_in[5];
    const float* wx2   = (const float*)d_in[6];
    const float* wh2   = (const float*)d_in[7];
    const float* b2    = (const float*)d_in[8];
    const float* fc2_w = (const float*)d_in[9];
    const float* fc2_b = (const float*)d_in[10];
    float* out = (float*)d_out;

    char* ws = (char*)d_ws;
    size_t off = 0;
    auto carve = [&](size_t bytes) -> char* {
        char* p = ws + off; off += (bytes + 255) & ~(size_t)255; return p;
    };
    const size_t WSZ = (size_t)4096*1024*2;               // 8.4 MB per weight half
    bf16*  wx1h = (bf16*) carve(WSZ);   bf16* wx1l = (bf16*) carve(WSZ);
    bf16*  wh1h = (bf16*) carve(WSZ);   bf16* wh1l = (bf16*) carve(WSZ);
    bf16*  wx2h = (bf16*) carve(WSZ);   bf16* wx2l = (bf16*) carve(WSZ);
    bf16*  wh2h = (bf16*) carve(WSZ);   bf16* wh2l = (bf16*) carve(WSZ);
    bf16*  fc1h = (bf16*) carve((size_t)1024*512*2);
    bf16*  fc1l = (bf16*) carve((size_t)1024*512*2);
    bf16*  fc2h = (bf16*) carve((size_t)1024*1024*2);
    bf16*  fc2l = (bf16*) carve((size_t)1024*1024*2);
    float* preA = (float*)carve((size_t)512*4096*4);      // 8.4 MB
    float* preB = (float*)carve((size_t)512*4096*4);      // 8.4 MB
    float* h0   = (float*)carve((size_t)512*1024*4);
    float* h1   = (float*)carve((size_t)512*1024*4);
    float* c0   = (float*)carve((size_t)512*1024*4);
    float* c1   = (float*)carve((size_t)512*1024*4);
    const size_t xfull_bytes = (size_t)512*64*1024*4;     // fc1 out fp32, all t: 134 MB
    bool xfull = (off + xfull_bytes) <= ws_size;
    float* x = (float*)carve(xfull ? xfull_bytes : (size_t)512*1024*4);

    hipMemsetAsync(h0, 0, (size_t)512*1024*4, stream);
    hipMemsetAsync(h1, 0, (size_t)512*1024*4, stream);
    hipMemsetAsync(c0, 0, (size_t)512*1024*4, stream);
    hipMemsetAsync(c1, 0, (size_t)512*1024*4, stream);

    // one-time weight splits (per launch)
    convert_split<<<2048, 256, 0, stream>>>(wx1, wx1h, wx1l, 4*1024*1024/8);
    convert_split<<<2048, 256, 0, stream>>>(wx2, wx2h, wx2l, 4*1024*1024/8);
    convert_split<<<256,  256, 0, stream>>>(fc1_w, fc1h, fc1l, 1024*512/8);
    convert_split<<<512,  256, 0, stream>>>(fc2_w, fc2h, fc2l, 1024*1024/8);
    transpose_wh_split<<<dim3(16,16,8), 256, 0, stream>>>(wh1, wh2, wh1h, wh1l, wh2h, wh2l);

    if (xfull) {  // fc1 for all timesteps: M=32768, N=1024, K=512
        gemm3<<<dim3(256,8,1), 256, 0, stream>>>(
            obs, 512, fc1h, fc1l, 512, 512, fc1_b, x, 1024,
            nullptr, 0, nullptr, nullptr, 0, 64, nullptr, nullptr, 0);
    }

    for (int st = 0; st < 64; ++st) {
        const float* xt; int ldx;
        if (xfull) { xt = x + (size_t)st*1024; ldx = 64*1024; }
        else {
            gemm3<<<dim3(4,8,1), 256, 0, stream>>>(
                obs + (size_t)st*512, 64*512, fc1h, fc1l, 512, 512, fc1_b, x, 1024,
                nullptr, 0, nullptr, nullptr, 0, 64, nullptr, nullptr, 0);
            xt = x; ldx = 1024;
        }
        // layer 1: preA = x_t @ wx1^T ; preB = h0 @ wh1  (z-split, 256 WGs)
        gemm3<<<dim3(4,32,2), 256, 0, stream>>>(
            xt, ldx,  wx1h, wx1l, 1024, 1024, nullptr, preA, 4096,
            h0, 1024, wh1h, wh1l, 1024, 1024, nullptr, preB, 4096);
        lstm_cell<<<512, 256, 0, stream>>>(preA, preB, b1, c0, h0);
        // layer 2: preA = h0 @ wx2^T ; preB = h1 @ wh2
        gemm3<<<dim3(4,32,2), 256, 0, stream>>>(
            h0, 1024, wx2h, wx2l, 1024, 1024, nullptr, preA, 4096,
            h1, 1024, wh2h, wh2l, 1024, 1024, nullptr, preB, 4096);
        lstm_cell<<<512, 256, 0, stream>>>(preA, preB, b2, c1, h1);
    }

    // fc2: logit = h1 @ fc2_w^T + fc2_b  -> d_out[0 : 512*1024) as fp32
    gemm3<<<dim3(4,8,1), 256, 0, stream>>>(
        h1, 1024, fc2h, fc2l, 1024, 1024, fc2_b, out, 1024,
        nullptr, 0, nullptr, nullptr, 0, 64, nullptr, nullptr, 0);
    pack_out<<<2048, 256, 0, stream>>>(h0, h1, c0, c1, out);
}

// Round 4
// 4213.325 us; speedup vs baseline: 2.5468x; 2.5468x over previous
//
#include <hip/hip_runtime.h>
#include <hip/hip_bf16.h>
#include <hip/hip_fp16.h>

using half_t = _Float16;
typedef __attribute__((ext_vector_type(8))) _Float16 f16x8;  // 8 fp16 = 4 VGPRs (MFMA frag)
typedef __attribute__((ext_vector_type(4))) float f32x4;

#define LN_EPS 1e-5f

// async global->LDS, 16B per lane. gptr is PER-LANE, ldsbase is wave-uniform;
// HW writes ldsbase + lane*16.  [m97/m173 pattern]
__device__ inline void gll16(const void* g, void* ldsbase) {
    __builtin_amdgcn_global_load_lds(
        (const __attribute__((address_space(1))) void*)g,
        (__attribute__((address_space(3))) void*)ldsbase, 16, 0, 0);
}

// ---------------------------------------------------------------------------
// fp16 GEMM: C[M,N] = A[M,K] * B^T  (B stored N x K row-major) [+ fp32 bias]
// tiles 128x128, BK=64, 256 threads (4 waves, each 64x64 = 4x4 frags 16x16x32)
// LDS slot s (16B chunks): row = s>>3, holds chunk (s&7)^(row&7)  (XOR swizzle;
// swizzle applied on the per-lane GLOBAL address, LDS written linearly by
// global_load_lds, read side applies the same XOR).
// blockIdx.z selects one of two independent (A,B,C) sets -> one launch runs
// the x-part and h-part of a cell concurrently.
// ---------------------------------------------------------------------------
template<int OUTHALF>   // 1 = fp16 C, 0 = fp32 C
__global__ __launch_bounds__(256) void gemm_h(
    const half_t* __restrict__ A0, int lda0, const half_t* __restrict__ B0, int ldb0, int K0,
    const float* __restrict__ bias0, void* __restrict__ C0, int ldc0,
    const half_t* __restrict__ A1, int lda1, const half_t* __restrict__ B1, int ldb1, int K1,
    const float* __restrict__ bias1, void* __restrict__ C1, int ldc1)
{
    const half_t *A, *B; const float* bias; void* C; int lda, ldb, K, ldc;
    if (blockIdx.z == 0) { A=A0; B=B0; bias=bias0; C=C0; lda=lda0; ldb=ldb0; K=K0; ldc=ldc0; }
    else                 { A=A1; B=B1; bias=bias1; C=C1; lda=lda1; ldb=ldb1; K=K1; ldc=ldc1; }

    __shared__ __align__(16) unsigned char sA[128*64*2];   // 16 KB
    __shared__ __align__(16) unsigned char sB[128*64*2];   // 16 KB

    const int t  = threadIdx.x;
    const int l  = t & 63;
    const int w  = t >> 6;
    const int wr = (w >> 1) * 64;     // wave row base within tile
    const int wc = (w & 1)  * 64;     // wave col base within tile
    const int rowbase = blockIdx.x * 128;
    const int colbase = blockIdx.y * 128;

    f32x4 acc[4][4];
    #pragma unroll
    for (int m = 0; m < 4; ++m)
        #pragma unroll
        for (int n = 0; n < 4; ++n) acc[m][n] = (f32x4)(0.f);

    const int nkt = K >> 6;

    for (int kt = 0; kt < nkt; ++kt) {
        const int ko = kt * 64;
        // stage A,B tiles: 4 segments/wave each side, 1 KB per instruction
        #pragma unroll
        for (int i = 0; i < 4; ++i) {
            int s   = (w*4 + i)*64 + l;            // slot this lane fills
            int row = s >> 3;
            int ch  = ((s & 7) ^ (row & 7)) * 8;   // swizzled source chunk
            gll16(A + (size_t)(rowbase+row)*lda + ko + ch, &sA[(w*4 + i)*1024]);
            gll16(B + (size_t)(colbase+row)*ldb + ko + ch, &sB[(w*4 + i)*1024]);
        }
        __syncthreads();                           // vmcnt(0) drain + barrier
        #pragma unroll
        for (int kk = 0; kk < 2; ++kk) {
            const int chunk = kk*4 + (l >> 4);
            f16x8 bfr[4];
            #pragma unroll
            for (int n = 0; n < 4; ++n) {
                int rowb = wc + n*16 + (l & 15);
                bfr[n] = *(const f16x8*)&sB[rowb*128 + ((chunk ^ (rowb & 7)) << 4)];
            }
            #pragma unroll
            for (int m = 0; m < 4; ++m) {
                int rowa = wr + m*16 + (l & 15);
                f16x8 af = *(const f16x8*)&sA[rowa*128 + ((chunk ^ (rowa & 7)) << 4)];
                #pragma unroll
                for (int n = 0; n < 4; ++n)
                    acc[m][n] = __builtin_amdgcn_mfma_f32_16x16x32_f16(af, bfr[n], acc[m][n], 0, 0, 0);
            }
        }
        __syncthreads();                           // reads done before next overwrite
    }

    // epilogue: C/D layout col = lane&15, row = (lane>>4)*4 + reg  [m89/m91]
    #pragma unroll
    for (int m = 0; m < 4; ++m) {
        int row0 = rowbase + wr + m*16 + (l >> 4)*4;
        #pragma unroll
        for (int n = 0; n < 4; ++n) {
            int col = colbase + wc + n*16 + (l & 15);
            float bv = bias ? bias[col] : 0.f;
            #pragma unroll
            for (int r = 0; r < 4; ++r) {
                float v = acc[m][n][r] + bv;
                if (OUTHALF) ((half_t*)C)[(size_t)(row0+r)*ldc + col] = (half_t)v;
                else         ((float*)C)[(size_t)(row0+r)*ldc + col] = v;
            }
        }
    }
}

// ---------------------------------------------------------------------------
// LN-LSTM cell pointwise: pre = preA + preB + b ; gates i,f,o,ct ;
// c = LayerNorm(f*c + i*ct) ; h = o*tanh(c) -> fp16 (recurrence) + fp32 (out).
// One block (256 thr) per batch row.
// ---------------------------------------------------------------------------
__device__ inline float block_sum(float v, float* sred) {
    #pragma unroll
    for (int off = 32; off; off >>= 1) v += __shfl_down(v, off, 64);
    __syncthreads();
    if ((threadIdx.x & 63) == 0) sred[threadIdx.x >> 6] = v;
    __syncthreads();
    return sred[0] + sred[1] + sred[2] + sred[3];
}

__global__ __launch_bounds__(256) void lstm_cell(
    const float* __restrict__ preA, const float* __restrict__ preB,
    const float* __restrict__ bias,           // (4,1024) gate-major, fp32
    float* __restrict__ c_state, half_t* __restrict__ h16, float* __restrict__ h32)
{
    __shared__ float sred[4];
    const int b = blockIdx.x, t = threadIdx.x;
    float cn[4], og[4];
    float s = 0.f;
    #pragma unroll
    for (int j = 0; j < 4; ++j) {
        int h = t + j*256;
        size_t p = (size_t)b*4096 + h;
        float pi = preA[p]        + preB[p]        + bias[h];
        float pf = preA[p + 1024] + preB[p + 1024] + bias[h + 1024];
        float po = preA[p + 2048] + preB[p + 2048] + bias[h + 2048];
        float pc = preA[p + 3072] + preB[p + 3072] + bias[h + 3072];
        float ig = 1.f / (1.f + expf(-pi));
        float fg = 1.f / (1.f + expf(-pf));
        og[j]    = 1.f / (1.f + expf(-po));
        float ct = tanhf(pc);
        float v  = fg * c_state[(size_t)b*1024 + h] + ig * ct;
        cn[j] = v; s += v;
    }
    float mu  = block_sum(s, sred) * (1.f/1024.f);
    float vs = 0.f;
    #pragma unroll
    for (int j = 0; j < 4; ++j) { float d = cn[j] - mu; vs += d*d; }
    float var = block_sum(vs, sred) * (1.f/1024.f);
    float rs  = rsqrtf(var + LN_EPS);
    #pragma unroll
    for (int j = 0; j < 4; ++j) {
        int h = t + j*256;
        float cv = (cn[j] - mu) * rs;
        float hv = og[j] * tanhf(cv);
        c_state[(size_t)b*1024 + h] = cv;
        h16[(size_t)b*1024 + h] = (half_t)hv;
        h32[(size_t)b*1024 + h] = hv;
    }
}

// ---------------------------------------------------------------------------
// One-time transpose+convert wh[g] (K x N fp32) -> wh_t[g] (N x K fp16).
// grid (16,16,8): z<4 -> wh1 gate z ; z>=4 -> wh2 gate z-4. 64x64 LDS tiles.
// ---------------------------------------------------------------------------
__global__ __launch_bounds__(256) void transpose_wh_cvt(
    const float* __restrict__ wh1, const float* __restrict__ wh2,
    half_t* __restrict__ o1, half_t* __restrict__ o2)
{
    __shared__ float tile[64][65];
    const int z = blockIdx.z;
    const float* src = (z < 4 ? wh1 : wh2) + (size_t)(z & 3) * 1024 * 1024;
    half_t*      dst = (z < 4 ? o1  : o2 ) + (size_t)(z & 3) * 1024 * 1024;
    const int kb = blockIdx.x * 64, nb = blockIdx.y * 64;
    const int t = threadIdx.x;
    #pragma unroll
    for (int i = 0; i < 16; ++i) {
        int idx = t + i*256, r = idx >> 6, c = idx & 63;
        tile[r][c] = src[(size_t)(kb + r)*1024 + nb + c];
    }
    __syncthreads();
    #pragma unroll
    for (int i = 0; i < 16; ++i) {
        int idx = t + i*256, r = idx >> 6, c = idx & 63;
        dst[(size_t)(nb + r)*1024 + kb + c] = (half_t)tile[c][r];
    }
}

// fp32 -> fp16 bulk convert, 8 elems/thread
__global__ __launch_bounds__(256) void cvt_f32_f16(
    const float* __restrict__ in, half_t* __restrict__ out, int n8)
{
    int i = blockIdx.x * 256 + threadIdx.x;
    if (i >= n8) return;
    float4 lo = ((const float4*)in)[2*i];
    float4 hi = ((const float4*)in)[2*i + 1];
    union { uint4 v; half_t h[8]; } r;
    r.h[0]=(half_t)lo.x; r.h[1]=(half_t)lo.y; r.h[2]=(half_t)lo.z; r.h[3]=(half_t)lo.w;
    r.h[4]=(half_t)hi.x; r.h[5]=(half_t)hi.y; r.h[6]=(half_t)hi.z; r.h[7]=(half_t)hi.w;
    ((uint4*)out)[i] = r.v;
}

// ---------------------------------------------------------------------------
// Final packing: d_out = [logit (fp32, written by fc2 gemm) | h0 | h1 | c0 | c1]
// ---------------------------------------------------------------------------
__global__ __launch_bounds__(256) void pack_out(
    const float* __restrict__ h0, const float* __restrict__ h1,
    const float* __restrict__ c0, const float* __restrict__ c1, float* __restrict__ out)
{
    const int NSZ = 512 * 1024;
    int i = blockIdx.x * 256 + threadIdx.x;
    out[NSZ     + i] = h0[i];
    out[2*NSZ   + i] = h1[i];
    out[3*NSZ   + i] = c0[i];
    out[4*NSZ   + i] = c1[i];
}

extern "C" void kernel_launch(void* const* d_in, const int* in_sizes, int n_in,
                              void* d_out, int out_size, void* d_ws, size_t ws_size,
                              hipStream_t stream)
{
    const float* obs   = (const float*)d_in[0];
    const float* fc1_w = (const float*)d_in[1];
    const float* fc1_b = (const float*)d_in[2];
    const float* wx1   = (const float*)d_in[3];
    const float* wh1   = (const float*)d_in[4];
    const float* b1    = (const float*)d_in[5];
    const float* wx2   = (const float*)d_in[6];
    const float* wh2   = (const float*)d_in[7];
    const float* b2    = (const float*)d_in[8];
    const float* fc2_w = (const float*)d_in[9];
    const float* fc2_b = (const float*)d_in[10];
    float* out = (float*)d_out;

    char* ws = (char*)d_ws;
    size_t off = 0;
    auto carve = [&](size_t bytes) -> char* {
        char* p = ws + off; off += (bytes + 255) & ~(size_t)255; return p;
    };
    half_t* obs16 = (half_t*)carve((size_t)512*64*512*2);   // 33.6 MB
    half_t* wx1c  = (half_t*)carve((size_t)4096*1024*2);    //  8.4 MB
    half_t* wh1t  = (half_t*)carve((size_t)4096*1024*2);    //  8.4 MB
    half_t* wx2c  = (half_t*)carve((size_t)4096*1024*2);    //  8.4 MB
    half_t* wh2t  = (half_t*)carve((size_t)4096*1024*2);    //  8.4 MB
    half_t* fc1c  = (half_t*)carve((size_t)1024*512*2);     //  1.0 MB
    half_t* fc2c  = (half_t*)carve((size_t)1024*1024*2);    //  2.1 MB
    float*  preA  = (float*) carve((size_t)512*4096*4);     //  8.4 MB
    float*  preB  = (float*) carve((size_t)512*4096*4);     //  8.4 MB
    half_t* h0s   = (half_t*)carve((size_t)512*1024*2);
    half_t* h1s   = (half_t*)carve((size_t)512*1024*2);
    float*  h0f   = (float*) carve((size_t)512*1024*4);
    float*  h1f   = (float*) carve((size_t)512*1024*4);
    float*  c0    = (float*) carve((size_t)512*1024*4);
    float*  c1    = (float*) carve((size_t)512*1024*4);
    const size_t xfull_bytes = (size_t)512*64*1024*2;       // fc1 out fp16, all t: 67 MB
    bool xfull = (off + xfull_bytes) <= ws_size;
    half_t* x = (half_t*)carve(xfull ? xfull_bytes : (size_t)512*1024*2);

    hipMemsetAsync(h0s, 0, (size_t)512*1024*2, stream);
    hipMemsetAsync(h1s, 0, (size_t)512*1024*2, stream);
    hipMemsetAsync(h0f, 0, (size_t)512*1024*4, stream);
    hipMemsetAsync(h1f, 0, (size_t)512*1024*4, stream);
    hipMemsetAsync(c0,  0, (size_t)512*1024*4, stream);
    hipMemsetAsync(c1,  0, (size_t)512*1024*4, stream);

    // one-time conversions (per launch)
    cvt_f32_f16<<<8192, 256, 0, stream>>>(obs,   obs16, 512*64*512/8);
    cvt_f32_f16<<<2048, 256, 0, stream>>>(wx1,   wx1c,  4*1024*1024/8);
    cvt_f32_f16<<<2048, 256, 0, stream>>>(wx2,   wx2c,  4*1024*1024/8);
    cvt_f32_f16<<<256,  256, 0, stream>>>(fc1_w, fc1c,  1024*512/8);
    cvt_f32_f16<<<512,  256, 0, stream>>>(fc2_w, fc2c,  1024*1024/8);
    transpose_wh_cvt<<<dim3(16,16,8), 256, 0, stream>>>(wh1, wh2, wh1t, wh2t);

    if (xfull) {  // fc1 for all timesteps: M=32768, N=1024, K=512
        gemm_h<1><<<dim3(256,8,1), 256, 0, stream>>>(
            obs16, 512, fc1c, 512, 512, fc1_b, x, 1024,
            nullptr, 0, nullptr, 0, 64, nullptr, nullptr, 0);
    }

    for (int st = 0; st < 64; ++st) {
        const half_t* xt; int ldx;
        if (xfull) { xt = x + (size_t)st*1024; ldx = 64*1024; }
        else {
            gemm_h<1><<<dim3(4,8,1), 256, 0, stream>>>(
                obs16 + (size_t)st*512, 64*512, fc1c, 512, 512, fc1_b, x, 1024,
                nullptr, 0, nullptr, 0, 64, nullptr, nullptr, 0);
            xt = x; ldx = 1024;
        }
        // layer 1: preA = x_t @ wx1^T ; preB = h0 @ wh1  (z-split, 256 WGs)
        gemm_h<0><<<dim3(4,32,2), 256, 0, stream>>>(
            xt, ldx,   wx1c, 1024, 1024, nullptr, preA, 4096,
            h0s, 1024, wh1t, 1024, 1024, nullptr, preB, 4096);
        lstm_cell<<<512, 256, 0, stream>>>(preA, preB, b1, c0, h0s, h0f);
        // layer 2: preA = h0 @ wx2^T ; preB = h1 @ wh2
        gemm_h<0><<<dim3(4,32,2), 256, 0, stream>>>(
            h0s, 1024, wx2c, 1024, 1024, nullptr, preA, 4096,
            h1s, 1024, wh2t, 1024, 1024, nullptr, preB, 4096);
        lstm_cell<<<512, 256, 0, stream>>>(preA, preB, b2, c1, h1s, h1f);
    }

    // fc2: logit = h1 @ fc2_w^T + fc2_b  -> d_out[0 : 512*1024) as fp32
    gemm_h<0><<<dim3(4,8,1), 256, 0, stream>>>(
        h1s, 1024, fc2c, 1024, 1024, fc2_b, out, 1024,
        nullptr, 0, nullptr, 0, 64, nullptr, nullptr, 0);
    pack_out<<<2048, 256, 0, stream>>>(h0f, h1f, c0, c1, out);
}

// Round 5
// 3719.618 us; speedup vs baseline: 2.8848x; 1.1327x over previous
//
#include <hip/hip_runtime.h>
#include <hip/hip_bf16.h>
#include <hip/hip_fp16.h>

using half_t = _Float16;
typedef __attribute__((ext_vector_type(8))) _Float16 f16x8;  // 8 fp16 = 4 VGPRs (MFMA frag)
typedef __attribute__((ext_vector_type(4))) _Float16 f16x4;
typedef __attribute__((ext_vector_type(4))) float f32x4;

#define LN_EPS 1e-5f

// async global->LDS, 16B per lane. gptr is PER-LANE, ldsbase is wave-uniform;
// HW writes ldsbase + lane*16.  [m97/m173 pattern]
__device__ inline void gll16(const void* g, void* ldsbase) {
    __builtin_amdgcn_global_load_lds(
        (const __attribute__((address_space(1))) void*)g,
        (__attribute__((address_space(3))) void*)ldsbase, 16, 0, 0);
}

// ---------------------------------------------------------------------------
// fp16 GEMM: C[M,N] = A[M,K] * B^T  (B stored N x K row-major) [+ fp32 bias]
// tiles 128x128, BK=64, 256 threads (4 waves, each 64x64 = 4x4 frags 16x16x32)
// LDS slot s (16B chunks): row = s>>3, holds chunk (s&7)^(row&7)  (XOR swizzle
// applied on the per-lane GLOBAL address; LDS written linearly by
// global_load_lds, read side applies the same XOR).
// 2-phase pipeline (T3-minimum): stage(k+1) issued BEFORE compute(k); the
// top-of-iter __syncthreads (vmcnt(0)+barrier) then waits on loads that had a
// full compute phase to land -> latency hidden even at 1 WG/CU.
// blockIdx.z selects one of two independent (A,B,C) sets.
// ---------------------------------------------------------------------------
template<int OUTHALF>   // 1 = fp16 C, 0 = fp32 C
__global__ __launch_bounds__(256) void gemm_h(
    const half_t* __restrict__ A0, int lda0, const half_t* __restrict__ B0, int ldb0, int K0,
    const float* __restrict__ bias0, void* __restrict__ C0, int ldc0,
    const half_t* __restrict__ A1, int lda1, const half_t* __restrict__ B1, int ldb1, int K1,
    const float* __restrict__ bias1, void* __restrict__ C1, int ldc1)
{
    const half_t *A, *B; const float* bias; void* C; int lda, ldb, K, ldc;
    if (blockIdx.z == 0) { A=A0; B=B0; bias=bias0; C=C0; lda=lda0; ldb=ldb0; K=K0; ldc=ldc0; }
    else                 { A=A1; B=B1; bias=bias1; C=C1; lda=lda1; ldb=ldb1; K=K1; ldc=ldc1; }

    __shared__ __align__(16) unsigned char sA[2][128*64*2];   // 2 x 16 KB
    __shared__ __align__(16) unsigned char sB[2][128*64*2];   // 2 x 16 KB

    const int t  = threadIdx.x;
    const int l  = t & 63;
    const int w  = t >> 6;
    const int wr = (w >> 1) * 64;     // wave row base within tile
    const int wc = (w & 1)  * 64;     // wave col base within tile
    const int rowbase = blockIdx.x * 128;
    const int colbase = blockIdx.y * 128;

    f32x4 acc[4][4];
    #pragma unroll
    for (int m = 0; m < 4; ++m)
        #pragma unroll
        for (int n = 0; n < 4; ++n) acc[m][n] = (f32x4)(0.f);

    // per-lane staging source geometry (slot s = (w*4+i)*64 + l)
    int srow[4], sch[4];
    #pragma unroll
    for (int i = 0; i < 4; ++i) {
        int s = (w*4 + i)*64 + l;
        srow[i] = s >> 3;
        sch[i]  = ((s & 7) ^ (srow[i] & 7)) * 8;
    }

    const int nkt = K >> 6;

    auto stage = [&](int kt, int buf) {
        const int ko = kt * 64;
        #pragma unroll
        for (int i = 0; i < 4; ++i) {
            gll16(A + (size_t)(rowbase+srow[i])*lda + ko + sch[i], &sA[buf][(w*4+i)*1024]);
            gll16(B + (size_t)(colbase+srow[i])*ldb + ko + sch[i], &sB[buf][(w*4+i)*1024]);
        }
    };

    stage(0, 0);
    for (int kt = 0; kt < nkt; ++kt) {
        const int buf = kt & 1;
        __syncthreads();                 // vmcnt(0): buf ready; WAR-safe for buf^1
        if (kt + 1 < nkt) stage(kt + 1, buf ^ 1);   // overlaps with compute below
        #pragma unroll
        for (int kk = 0; kk < 2; ++kk) {
            const int chunk = kk*4 + (l >> 4);
            f16x8 bfr[4];
            #pragma unroll
            for (int n = 0; n < 4; ++n) {
                int rowb = wc + n*16 + (l & 15);
                bfr[n] = *(const f16x8*)&sB[buf][rowb*128 + ((chunk ^ (rowb & 7)) << 4)];
            }
            #pragma unroll
            for (int m = 0; m < 4; ++m) {
                int rowa = wr + m*16 + (l & 15);
                f16x8 af = *(const f16x8*)&sA[buf][rowa*128 + ((chunk ^ (rowa & 7)) << 4)];
                #pragma unroll
                for (int n = 0; n < 4; ++n)
                    acc[m][n] = __builtin_amdgcn_mfma_f32_16x16x32_f16(af, bfr[n], acc[m][n], 0, 0, 0);
            }
        }
    }

    // epilogue: C/D layout col = lane&15, row = (lane>>4)*4 + reg  [m89/m91]
    #pragma unroll
    for (int m = 0; m < 4; ++m) {
        int row0 = rowbase + wr + m*16 + (l >> 4)*4;
        #pragma unroll
        for (int n = 0; n < 4; ++n) {
            int col = colbase + wc + n*16 + (l & 15);
            float bv = bias ? bias[col] : 0.f;
            #pragma unroll
            for (int r = 0; r < 4; ++r) {
                float v = acc[m][n][r] + bv;
                if (OUTHALF) ((half_t*)C)[(size_t)(row0+r)*ldc + col] = (half_t)v;
                else         ((float*)C)[(size_t)(row0+r)*ldc + col] = v;
            }
        }
    }
}

// ---------------------------------------------------------------------------
// LN-LSTM cell pointwise: pre = preA + preB + b ; gates i,f,o,ct ;
// c = LayerNorm(f*c + i*ct) ; h = o*tanh(c) -> fp16 (recurrence) + fp32 (out).
// One block (256 thr) per batch row; each thread owns 4 contiguous h indices
// so all loads/stores are 8-16B vectors (G13).
// ---------------------------------------------------------------------------
__device__ inline float block_sum(float v, float* sred) {
    #pragma unroll
    for (int off = 32; off; off >>= 1) v += __shfl_down(v, off, 64);
    __syncthreads();
    if ((threadIdx.x & 63) == 0) sred[threadIdx.x >> 6] = v;
    __syncthreads();
    return sred[0] + sred[1] + sred[2] + sred[3];
}

__global__ __launch_bounds__(256) void lstm_cell(
    const half_t* __restrict__ preA, const half_t* __restrict__ preB,
    const float* __restrict__ bias,           // (4,1024) gate-major, fp32
    float* __restrict__ c_state, half_t* __restrict__ h16, float* __restrict__ h32)
{
    __shared__ float sred[4];
    const int b = blockIdx.x, t = threadIdx.x;
    const int hi = t * 4;
    const size_t pb = (size_t)b * 4096 + hi;
    const size_t cb = (size_t)b * 1024 + hi;

    float pre[4][4];
    #pragma unroll
    for (int g = 0; g < 4; ++g) {
        f16x4 pa = *(const f16x4*)&preA[pb + g*1024];
        f16x4 pv = *(const f16x4*)&preB[pb + g*1024];
        float4 bs = *(const float4*)&bias[g*1024 + hi];
        pre[g][0] = (float)pa[0] + (float)pv[0] + bs.x;
        pre[g][1] = (float)pa[1] + (float)pv[1] + bs.y;
        pre[g][2] = (float)pa[2] + (float)pv[2] + bs.z;
        pre[g][3] = (float)pa[3] + (float)pv[3] + bs.w;
    }
    float4 c4 = *(const float4*)&c_state[cb];
    float co[4] = {c4.x, c4.y, c4.z, c4.w};

    float cn[4], og[4], s = 0.f;
    #pragma unroll
    for (int j = 0; j < 4; ++j) {
        float ig = 1.f / (1.f + expf(-pre[0][j]));
        float fg = 1.f / (1.f + expf(-pre[1][j]));
        og[j]    = 1.f / (1.f + expf(-pre[2][j]));
        float ct = tanhf(pre[3][j]);
        cn[j] = fg * co[j] + ig * ct;
        s += cn[j];
    }
    float mu  = block_sum(s, sred) * (1.f/1024.f);
    float vs = 0.f;
    #pragma unroll
    for (int j = 0; j < 4; ++j) { float d = cn[j] - mu; vs += d*d; }
    float var = block_sum(vs, sred) * (1.f/1024.f);
    float rs  = rsqrtf(var + LN_EPS);

    float4 cw, hw; f16x4 h16w;
    float cvv[4], hvv[4];
    #pragma unroll
    for (int j = 0; j < 4; ++j) {
        cvv[j] = (cn[j] - mu) * rs;
        hvv[j] = og[j] * tanhf(cvv[j]);
        h16w[j] = (half_t)hvv[j];
    }
    cw.x=cvv[0]; cw.y=cvv[1]; cw.z=cvv[2]; cw.w=cvv[3];
    hw.x=hvv[0]; hw.y=hvv[1]; hw.z=hvv[2]; hw.w=hvv[3];
    *(float4*)&c_state[cb] = cw;
    *(f16x4*)&h16[cb]      = h16w;
    *(float4*)&h32[cb]     = hw;
}

// ---------------------------------------------------------------------------
// One-time transpose+convert wh[g] (K x N fp32) -> wh_t[g] (N x K fp16).
// grid (16,16,8): z<4 -> wh1 gate z ; z>=4 -> wh2 gate z-4. 64x64 LDS tiles.
// ---------------------------------------------------------------------------
__global__ __launch_bounds__(256) void transpose_wh_cvt(
    const float* __restrict__ wh1, const float* __restrict__ wh2,
    half_t* __restrict__ o1, half_t* __restrict__ o2)
{
    __shared__ float tile[64][65];
    const int z = blockIdx.z;
    const float* src = (z < 4 ? wh1 : wh2) + (size_t)(z & 3) * 1024 * 1024;
    half_t*      dst = (z < 4 ? o1  : o2 ) + (size_t)(z & 3) * 1024 * 1024;
    const int kb = blockIdx.x * 64, nb = blockIdx.y * 64;
    const int t = threadIdx.x;
    #pragma unroll
    for (int i = 0; i < 16; ++i) {
        int idx = t + i*256, r = idx >> 6, c = idx & 63;
        tile[r][c] = src[(size_t)(kb + r)*1024 + nb + c];
    }
    __syncthreads();
    #pragma unroll
    for (int i = 0; i < 16; ++i) {
        int idx = t + i*256, r = idx >> 6, c = idx & 63;
        dst[(size_t)(nb + r)*1024 + kb + c] = (half_t)tile[c][r];
    }
}

// fp32 -> fp16 bulk convert, 8 elems/thread
__global__ __launch_bounds__(256) void cvt_f32_f16(
    const float* __restrict__ in, half_t* __restrict__ out, int n8)
{
    int i = blockIdx.x * 256 + threadIdx.x;
    if (i >= n8) return;
    float4 lo = ((const float4*)in)[2*i];
    float4 hi = ((const float4*)in)[2*i + 1];
    union { uint4 v; half_t h[8]; } r;
    r.h[0]=(half_t)lo.x; r.h[1]=(half_t)lo.y; r.h[2]=(half_t)lo.z; r.h[3]=(half_t)lo.w;
    r.h[4]=(half_t)hi.x; r.h[5]=(half_t)hi.y; r.h[6]=(half_t)hi.z; r.h[7]=(half_t)hi.w;
    ((uint4*)out)[i] = r.v;
}

// ---------------------------------------------------------------------------
// Final packing: d_out = [logit (fp32, written by fc2 gemm) | h0 | h1 | c0 | c1]
// ---------------------------------------------------------------------------
__global__ __launch_bounds__(256) void pack_out(
    const float* __restrict__ h0, const float* __restrict__ h1,
    const float* __restrict__ c0, const float* __restrict__ c1, float* __restrict__ out)
{
    const int NSZ = 512 * 1024;
    int i = blockIdx.x * 256 + threadIdx.x;
    out[NSZ     + i] = h0[i];
    out[2*NSZ   + i] = h1[i];
    out[3*NSZ   + i] = c0[i];
    out[4*NSZ   + i] = c1[i];
}

extern "C" void kernel_launch(void* const* d_in, const int* in_sizes, int n_in,
                              void* d_out, int out_size, void* d_ws, size_t ws_size,
                              hipStream_t stream)
{
    const float* obs   = (const float*)d_in[0];
    const float* fc1_w = (const float*)d_in[1];
    const float* fc1_b = (const float*)d_in[2];
    const float* wx1   = (const float*)d_in[3];
    const float* wh1   = (const float*)d_in[4];
    const float* b1    = (const float*)d_in[5];
    const float* wx2   = (const float*)d_in[6];
    const float* wh2   = (const float*)d_in[7];
    const float* b2    = (const float*)d_in[8];
    const float* fc2_w = (const float*)d_in[9];
    const float* fc2_b = (const float*)d_in[10];
    float* out = (float*)d_out;

    char* ws = (char*)d_ws;
    size_t off = 0;
    auto carve = [&](size_t bytes) -> char* {
        char* p = ws + off; off += (bytes + 255) & ~(size_t)255; return p;
    };
    half_t* obs16 = (half_t*)carve((size_t)512*64*512*2);   // 33.6 MB
    half_t* wx1c  = (half_t*)carve((size_t)4096*1024*2);    //  8.4 MB
    half_t* wh1t  = (half_t*)carve((size_t)4096*1024*2);    //  8.4 MB
    half_t* wx2c  = (half_t*)carve((size_t)4096*1024*2);    //  8.4 MB
    half_t* wh2t  = (half_t*)carve((size_t)4096*1024*2);    //  8.4 MB
    half_t* fc1c  = (half_t*)carve((size_t)1024*512*2);     //  1.0 MB
    half_t* fc2c  = (half_t*)carve((size_t)1024*1024*2);    //  2.1 MB
    half_t* preA  = (half_t*)carve((size_t)512*4096*2);     //  4.2 MB
    half_t* preB  = (half_t*)carve((size_t)512*4096*2);     //  4.2 MB
    half_t* h0s   = (half_t*)carve((size_t)512*1024*2);
    half_t* h1s   = (half_t*)carve((size_t)512*1024*2);
    float*  h0f   = (float*) carve((size_t)512*1024*4);
    float*  h1f   = (float*) carve((size_t)512*1024*4);
    float*  c0    = (float*) carve((size_t)512*1024*4);
    float*  c1    = (float*) carve((size_t)512*1024*4);
    const size_t xfull_bytes = (size_t)512*64*1024*2;       // fc1 out fp16, all t: 67 MB
    bool xfull = (off + xfull_bytes) <= ws_size;
    half_t* x = (half_t*)carve(xfull ? xfull_bytes : (size_t)512*1024*2);

    hipMemsetAsync(h0s, 0, (size_t)512*1024*2, stream);
    hipMemsetAsync(h1s, 0, (size_t)512*1024*2, stream);
    hipMemsetAsync(h0f, 0, (size_t)512*1024*4, stream);
    hipMemsetAsync(h1f, 0, (size_t)512*1024*4, stream);
    hipMemsetAsync(c0,  0, (size_t)512*1024*4, stream);
    hipMemsetAsync(c1,  0, (size_t)512*1024*4, stream);

    // one-time conversions (per launch)
    cvt_f32_f16<<<8192, 256, 0, stream>>>(obs,   obs16, 512*64*512/8);
    cvt_f32_f16<<<2048, 256, 0, stream>>>(wx1,   wx1c,  4*1024*1024/8);
    cvt_f32_f16<<<2048, 256, 0, stream>>>(wx2,   wx2c,  4*1024*1024/8);
    cvt_f32_f16<<<256,  256, 0, stream>>>(fc1_w, fc1c,  1024*512/8);
    cvt_f32_f16<<<512,  256, 0, stream>>>(fc2_w, fc2c,  1024*1024/8);
    transpose_wh_cvt<<<dim3(16,16,8), 256, 0, stream>>>(wh1, wh2, wh1t, wh2t);

    if (xfull) {  // fc1 for all timesteps: M=32768, N=1024, K=512
        gemm_h<1><<<dim3(256,8,1), 256, 0, stream>>>(
            obs16, 512, fc1c, 512, 512, fc1_b, x, 1024,
            nullptr, 0, nullptr, 0, 64, nullptr, nullptr, 0);
    }

    for (int st = 0; st < 64; ++st) {
        const half_t* xt; int ldx;
        if (xfull) { xt = x + (size_t)st*1024; ldx = 64*1024; }
        else {
            gemm_h<1><<<dim3(4,8,1), 256, 0, stream>>>(
                obs16 + (size_t)st*512, 64*512, fc1c, 512, 512, fc1_b, x, 1024,
                nullptr, 0, nullptr, 0, 64, nullptr, nullptr, 0);
            xt = x; ldx = 1024;
        }
        // layer 1: preA = x_t @ wx1^T ; preB = h0 @ wh1  (z-split, 256 WGs)
        gemm_h<1><<<dim3(4,32,2), 256, 0, stream>>>(
            xt, ldx,   wx1c, 1024, 1024, nullptr, preA, 4096,
            h0s, 1024, wh1t, 1024, 1024, nullptr, preB, 4096);
        lstm_cell<<<512, 256, 0, stream>>>(preA, preB, b1, c0, h0s, h0f);
        // layer 2: preA = h0 @ wx2^T ; preB = h1 @ wh2
        gemm_h<1><<<dim3(4,32,2), 256, 0, stream>>>(
            h0s, 1024, wx2c, 1024, 1024, nullptr, preA, 4096,
            h1s, 1024, wh2t, 1024, 1024, nullptr, preB, 4096);
        lstm_cell<<<512, 256, 0, stream>>>(preA, preB, b2, c1, h1s, h1f);
    }

    // fc2: logit = h1 @ fc2_w^T + fc2_b  -> d_out[0 : 512*1024) as fp32
    gemm_h<0><<<dim3(4,8,1), 256, 0, stream>>>(
        h1s, 1024, fc2c, 1024, 1024, fc2_b, out, 1024,
        nullptr, 0, nullptr, 0, 64, nullptr, nullptr, 0);
    pack_out<<<2048, 256, 0, stream>>>(h0f, h1f, c0, c1, out);
}

// Round 6
// 3651.298 us; speedup vs baseline: 2.9388x; 1.0187x over previous
//
#include <hip/hip_runtime.h>
#include <hip/hip_bf16.h>
#include <hip/hip_fp16.h>

using half_t = _Float16;
typedef __attribute__((ext_vector_type(8))) _Float16 f16x8;  // 8 fp16 = 4 VGPRs (MFMA frag)
typedef __attribute__((ext_vector_type(4))) _Float16 f16x4;
typedef __attribute__((ext_vector_type(4))) float f32x4;

#define LN_EPS 1e-5f

// async global->LDS, 16B per lane. gptr is PER-LANE, ldsbase is wave-uniform;
// HW writes ldsbase + lane*16.  [m97/m173 pattern]
__device__ inline void gll16(const void* g, void* ldsbase) {
    __builtin_amdgcn_global_load_lds(
        (const __attribute__((address_space(1))) void*)g,
        (__attribute__((address_space(3))) void*)ldsbase, 16, 0, 0);
}

struct GArgs {
    const half_t* A;      // M x K (row-major, lda)
    const half_t* B;      // N x K (row-major, ldb)  -> C = A * B^T
    const float*  bias;   // len N or null
    void*         C;      // M x N (ldc), fp16 if outhalf else fp32
    int lda, ldb, K, ldc, outhalf;
};

// ---------------------------------------------------------------------------
// Multi-set fp16 GEMM: up to 3 independent C = A*B^T [+bias] in one launch.
// tiles 128x128, BK=64, 256 threads (4 waves, each 64x64 = 4x4 frags 16x16x32)
// LDS XOR swizzle on per-lane GLOBAL address; linear global_load_lds writes;
// read side applies the same XOR.  2-phase pipeline: stage(k+1) before
// compute(k) so the barrier's vmcnt(0) waits on loads aged a full phase.
// 1D grid, decoded so that column-panel y%8 == dispatch id %8 == XCD:
// a given weight panel is read by ONE XCD every launch -> L2-resident
// across the 64 timesteps.
// ---------------------------------------------------------------------------
__global__ __launch_bounds__(256) void gemm_ms(GArgs g0, GArgs g1, GArgs g2,
                                               int gx, int gz)
{
    // decode swizzled id -> (x, y, z); bijective for grid n = gx * gy * gz,
    // gy % 8 == 0:  d = (y%8) + 8*(x + gx*(z + gz*(y/8)))
    const int d   = blockIdx.x;
    const int ylo = d & 7;
    int r   = d >> 3;
    const int x  = r % gx;  r /= gx;
    const int z  = r % gz;
    const int y  = ylo + 8 * (r / gz);

    const GArgs g = (z == 0) ? g0 : (z == 1 ? g1 : g2);

    __shared__ __align__(16) unsigned char sA[2][128*64*2];   // 2 x 16 KB
    __shared__ __align__(16) unsigned char sB[2][128*64*2];   // 2 x 16 KB

    const int t  = threadIdx.x;
    const int l  = t & 63;
    const int w  = t >> 6;
    const int wr = (w >> 1) * 64;
    const int wc = (w & 1)  * 64;
    const int rowbase = x * 128;
    const int colbase = y * 128;

    f32x4 acc[4][4];
    #pragma unroll
    for (int m = 0; m < 4; ++m)
        #pragma unroll
        for (int n = 0; n < 4; ++n) acc[m][n] = (f32x4)(0.f);

    // per-lane staging source geometry (slot s = (w*4+i)*64 + l)
    int srow[4], sch[4];
    #pragma unroll
    for (int i = 0; i < 4; ++i) {
        int s = (w*4 + i)*64 + l;
        srow[i] = s >> 3;
        sch[i]  = ((s & 7) ^ (srow[i] & 7)) * 8;
    }

    const int nkt = g.K >> 6;

    auto stage = [&](int kt, int buf) {
        const int ko = kt * 64;
        #pragma unroll
        for (int i = 0; i < 4; ++i) {
            gll16(g.A + (size_t)(rowbase+srow[i])*g.lda + ko + sch[i], &sA[buf][(w*4+i)*1024]);
            gll16(g.B + (size_t)(colbase+srow[i])*g.ldb + ko + sch[i], &sB[buf][(w*4+i)*1024]);
        }
    };

    stage(0, 0);
    for (int kt = 0; kt < nkt; ++kt) {
        const int buf = kt & 1;
        __syncthreads();                 // vmcnt(0): buf ready; WAR-safe for buf^1
        if (kt + 1 < nkt) stage(kt + 1, buf ^ 1);
        #pragma unroll
        for (int kk = 0; kk < 2; ++kk) {
            const int chunk = kk*4 + (l >> 4);
            f16x8 bfr[4];
            #pragma unroll
            for (int n = 0; n < 4; ++n) {
                int rowb = wc + n*16 + (l & 15);
                bfr[n] = *(const f16x8*)&sB[buf][rowb*128 + ((chunk ^ (rowb & 7)) << 4)];
            }
            #pragma unroll
            for (int m = 0; m < 4; ++m) {
                int rowa = wr + m*16 + (l & 15);
                f16x8 af = *(const f16x8*)&sA[buf][rowa*128 + ((chunk ^ (rowa & 7)) << 4)];
                #pragma unroll
                for (int n = 0; n < 4; ++n)
                    acc[m][n] = __builtin_amdgcn_mfma_f32_16x16x32_f16(af, bfr[n], acc[m][n], 0, 0, 0);
            }
        }
    }

    // epilogue: C/D layout col = lane&15, row = (lane>>4)*4 + reg  [m89/m91]
    #pragma unroll
    for (int m = 0; m < 4; ++m) {
        int row0 = rowbase + wr + m*16 + (l >> 4)*4;
        #pragma unroll
        for (int n = 0; n < 4; ++n) {
            int col = colbase + wc + n*16 + (l & 15);
            float bv = g.bias ? g.bias[col] : 0.f;
            #pragma unroll
            for (int r2 = 0; r2 < 4; ++r2) {
                float v = acc[m][n][r2] + bv;
                if (g.outhalf) ((half_t*)g.C)[(size_t)(row0+r2)*g.ldc + col] = (half_t)v;
                else           ((float*)g.C)[(size_t)(row0+r2)*g.ldc + col] = v;
            }
        }
    }
}

// ---------------------------------------------------------------------------
// LN-LSTM cell pointwise: pre = preA + preB + b ; gates i,f,o,ct ;
// c = LayerNorm(f*c + i*ct) ; h = o*tanh(c) -> fp16 (recurrence) + fp32 (out).
// One block (256 thr) per batch row; thread owns 4 contiguous h indices.
// strideA/strideB: element stride between consecutive batch rows (lets preA
// point into the hoisted PA1[t] slice with stride 64*4096).
// ---------------------------------------------------------------------------
__device__ inline float block_sum(float v, float* sred) {
    #pragma unroll
    for (int off = 32; off; off >>= 1) v += __shfl_down(v, off, 64);
    __syncthreads();
    if ((threadIdx.x & 63) == 0) sred[threadIdx.x >> 6] = v;
    __syncthreads();
    return sred[0] + sred[1] + sred[2] + sred[3];
}

__global__ __launch_bounds__(256) void lstm_cell(
    const half_t* __restrict__ preA, long strideA,
    const half_t* __restrict__ preB, long strideB,
    const float* __restrict__ bias,           // (4,1024) gate-major, fp32
    float* __restrict__ c_state, half_t* __restrict__ h16, float* __restrict__ h32)
{
    __shared__ float sred[4];
    const int b = blockIdx.x, t = threadIdx.x;
    const int hi = t * 4;
    const size_t pa = (size_t)b * strideA + hi;
    const size_t pv = (size_t)b * strideB + hi;
    const size_t cb = (size_t)b * 1024 + hi;

    float pre[4][4];
    #pragma unroll
    for (int g = 0; g < 4; ++g) {
        f16x4 a4 = *(const f16x4*)&preA[pa + g*1024];
        f16x4 v4 = *(const f16x4*)&preB[pv + g*1024];
        float4 bs = *(const float4*)&bias[g*1024 + hi];
        pre[g][0] = (float)a4[0] + (float)v4[0] + bs.x;
        pre[g][1] = (float)a4[1] + (float)v4[1] + bs.y;
        pre[g][2] = (float)a4[2] + (float)v4[2] + bs.z;
        pre[g][3] = (float)a4[3] + (float)v4[3] + bs.w;
    }
    float4 c4 = *(const float4*)&c_state[cb];
    float co[4] = {c4.x, c4.y, c4.z, c4.w};

    float cn[4], og[4], s = 0.f;
    #pragma unroll
    for (int j = 0; j < 4; ++j) {
        float ig = 1.f / (1.f + expf(-pre[0][j]));
        float fg = 1.f / (1.f + expf(-pre[1][j]));
        og[j]    = 1.f / (1.f + expf(-pre[2][j]));
        float ct = tanhf(pre[3][j]);
        cn[j] = fg * co[j] + ig * ct;
        s += cn[j];
    }
    float mu  = block_sum(s, sred) * (1.f/1024.f);
    float vs = 0.f;
    #pragma unroll
    for (int j = 0; j < 4; ++j) { float d = cn[j] - mu; vs += d*d; }
    float var = block_sum(vs, sred) * (1.f/1024.f);
    float rs  = rsqrtf(var + LN_EPS);

    float4 cw, hw; f16x4 h16w;
    float cvv[4], hvv[4];
    #pragma unroll
    for (int j = 0; j < 4; ++j) {
        cvv[j] = (cn[j] - mu) * rs;
        hvv[j] = og[j] * tanhf(cvv[j]);
        h16w[j] = (half_t)hvv[j];
    }
    cw.x=cvv[0]; cw.y=cvv[1]; cw.z=cvv[2]; cw.w=cvv[3];
    hw.x=hvv[0]; hw.y=hvv[1]; hw.z=hvv[2]; hw.w=hvv[3];
    *(float4*)&c_state[cb] = cw;
    *(f16x4*)&h16[cb]      = h16w;
    *(float4*)&h32[cb]     = hw;
}

// ---------------------------------------------------------------------------
// One-time transpose+convert wh[g] (K x N fp32) -> wh_t[g] (N x K fp16).
// ---------------------------------------------------------------------------
__global__ __launch_bounds__(256) void transpose_wh_cvt(
    const float* __restrict__ wh1, const float* __restrict__ wh2,
    half_t* __restrict__ o1, half_t* __restrict__ o2)
{
    __shared__ float tile[64][65];
    const int z = blockIdx.z;
    const float* src = (z < 4 ? wh1 : wh2) + (size_t)(z & 3) * 1024 * 1024;
    half_t*      dst = (z < 4 ? o1  : o2 ) + (size_t)(z & 3) * 1024 * 1024;
    const int kb = blockIdx.x * 64, nb = blockIdx.y * 64;
    const int t = threadIdx.x;
    #pragma unroll
    for (int i = 0; i < 16; ++i) {
        int idx = t + i*256, r = idx >> 6, c = idx & 63;
        tile[r][c] = src[(size_t)(kb + r)*1024 + nb + c];
    }
    __syncthreads();
    #pragma unroll
    for (int i = 0; i < 16; ++i) {
        int idx = t + i*256, r = idx >> 6, c = idx & 63;
        dst[(size_t)(nb + r)*1024 + kb + c] = (half_t)tile[c][r];
    }
}

// fp32 -> fp16 bulk convert, 8 elems/thread
__global__ __launch_bounds__(256) void cvt_f32_f16(
    const float* __restrict__ in, half_t* __restrict__ out, int n8)
{
    int i = blockIdx.x * 256 + threadIdx.x;
    if (i >= n8) return;
    float4 lo = ((const float4*)in)[2*i];
    float4 hi = ((const float4*)in)[2*i + 1];
    union { uint4 v; half_t h[8]; } r;
    r.h[0]=(half_t)lo.x; r.h[1]=(half_t)lo.y; r.h[2]=(half_t)lo.z; r.h[3]=(half_t)lo.w;
    r.h[4]=(half_t)hi.x; r.h[5]=(half_t)hi.y; r.h[6]=(half_t)hi.z; r.h[7]=(half_t)hi.w;
    ((uint4*)out)[i] = r.v;
}

// d_out = [logit (fp32, written by fc2 gemm) | h0 | h1 | c0 | c1]
__global__ __launch_bounds__(256) void pack_out(
    const float* __restrict__ h0, const float* __restrict__ h1,
    const float* __restrict__ c0, const float* __restrict__ c1, float* __restrict__ out)
{
    const int NSZ = 512 * 1024;
    int i = blockIdx.x * 256 + threadIdx.x;
    out[NSZ     + i] = h0[i];
    out[2*NSZ   + i] = h1[i];
    out[3*NSZ   + i] = c0[i];
    out[4*NSZ   + i] = c1[i];
}

extern "C" void kernel_launch(void* const* d_in, const int* in_sizes, int n_in,
                              void* d_out, int out_size, void* d_ws, size_t ws_size,
                              hipStream_t stream)
{
    const float* obs   = (const float*)d_in[0];
    const float* fc1_w = (const float*)d_in[1];
    const float* fc1_b = (const float*)d_in[2];
    const float* wx1   = (const float*)d_in[3];
    const float* wh1   = (const float*)d_in[4];
    const float* b1    = (const float*)d_in[5];
    const float* wx2   = (const float*)d_in[6];
    const float* wh2   = (const float*)d_in[7];
    const float* b2    = (const float*)d_in[8];
    const float* fc2_w = (const float*)d_in[9];
    const float* fc2_b = (const float*)d_in[10];
    float* out = (float*)d_out;

    char* ws = (char*)d_ws;
    size_t off = 0;
    auto carve = [&](size_t bytes) -> char* {
        char* p = ws + off; off += (bytes + 255) & ~(size_t)255; return p;
    };
    half_t* obs16 = (half_t*)carve((size_t)512*64*512*2);   // 33.6 MB
    half_t* wx1c  = (half_t*)carve((size_t)4096*1024*2);    //  8.4 MB
    half_t* wh1t  = (half_t*)carve((size_t)4096*1024*2);
    half_t* wx2c  = (half_t*)carve((size_t)4096*1024*2);
    half_t* wh2t  = (half_t*)carve((size_t)4096*1024*2);
    half_t* fc1c  = (half_t*)carve((size_t)1024*512*2);
    half_t* fc2c  = (half_t*)carve((size_t)1024*1024*2);
    half_t* preA  = (half_t*)carve((size_t)512*4096*2);     //  4.2 MB
    half_t* preB  = (half_t*)carve((size_t)512*4096*2);     //  4.2 MB
    half_t* preB1 = (half_t*)carve((size_t)512*4096*2);     //  4.2 MB
    half_t* h0s   = (half_t*)carve((size_t)512*1024*2);
    half_t* h1s   = (half_t*)carve((size_t)512*1024*2);
    float*  h0f   = (float*) carve((size_t)512*1024*4);
    float*  h1f   = (float*) carve((size_t)512*1024*4);
    float*  c0    = (float*) carve((size_t)512*1024*4);
    float*  c1    = (float*) carve((size_t)512*1024*4);

    const size_t X_bytes   = (size_t)512*64*1024*2;         //  67 MB (fc1 out, all t)
    const size_t PA1_bytes = (size_t)512*64*4096*2;         // 268 MB (x@wx1^T, all t)
    bool modeB = (off + X_bytes) <= ws_size;                // X buffer fits
    half_t* X = (half_t*)carve(modeB ? X_bytes : (size_t)512*1024*2);
    bool modeA = modeB && (off + PA1_bytes) <= ws_size;     // + PA1 fits
    half_t* PA1 = modeA ? (half_t*)carve(PA1_bytes) : nullptr;

    hipMemsetAsync(h0s, 0, (size_t)512*1024*2, stream);
    hipMemsetAsync(h1s, 0, (size_t)512*1024*2, stream);
    hipMemsetAsync(c0,  0, (size_t)512*1024*4, stream);
    hipMemsetAsync(c1,  0, (size_t)512*1024*4, stream);
    if (modeA) hipMemsetAsync(preB1, 0, (size_t)512*4096*2, stream);  // h0(0)=0 -> preB1(0)=0

    // one-time conversions
    cvt_f32_f16<<<8192, 256, 0, stream>>>(obs,   obs16, 512*64*512/8);
    cvt_f32_f16<<<2048, 256, 0, stream>>>(wx1,   wx1c,  4*1024*1024/8);
    cvt_f32_f16<<<2048, 256, 0, stream>>>(wx2,   wx2c,  4*1024*1024/8);
    cvt_f32_f16<<<256,  256, 0, stream>>>(fc1_w, fc1c,  1024*512/8);
    cvt_f32_f16<<<512,  256, 0, stream>>>(fc2_w, fc2c,  1024*1024/8);
    transpose_wh_cvt<<<dim3(16,16,8), 256, 0, stream>>>(wh1, wh2, wh1t, wh2t);

    GArgs Z{};  // unused slot
    auto ga = [](const half_t* A, int lda, const half_t* B, int ldb, int K,
                 const float* bias, void* C, int ldc, int outhalf) {
        GArgs g; g.A=A; g.B=B; g.bias=bias; g.C=C;
        g.lda=lda; g.ldb=ldb; g.K=K; g.ldc=ldc; g.outhalf=outhalf; return g;
    };

    if (modeB) {  // X = obs @ fc1^T + b : M=32768, N=1024, K=512
        gemm_ms<<<256*8, 256, 0, stream>>>(
            ga(obs16, 512, fc1c, 512, 512, fc1_b, X, 1024, 1), Z, Z, 256, 1);
    }

    if (modeA) {
        // PA1 = X @ wx1^T : M=32768, N=4096, K=1024  (one big parallel GEMM)
        gemm_ms<<<256*32, 256, 0, stream>>>(
            ga(X, 1024, wx1c, 1024, 1024, nullptr, PA1, 4096, 1), Z, Z, 256, 1);

        for (int st = 0; st < 64; ++st) {
            // cell1: pre1 = PA1[:,st,:] + preB1 + b1
            lstm_cell<<<512, 256, 0, stream>>>(
                PA1 + (size_t)st*4096, (long)64*4096, preB1, 4096, b1, c0, h0s, h0f);
            // triple: preA2 = h0@wx2^T ; preB2 = h1@wh2t^T ; preB1(t+1) = h0@wh1t^T
            gemm_ms<<<4*32*3, 256, 0, stream>>>(
                ga(h0s, 1024, wx2c, 1024, 1024, nullptr, preA, 4096, 1),
                ga(h1s, 1024, wh2t, 1024, 1024, nullptr, preB, 4096, 1),
                ga(h0s, 1024, wh1t, 1024, 1024, nullptr, preB1, 4096, 1), 4, 3);
            lstm_cell<<<512, 256, 0, stream>>>(preA, 4096, preB, 4096, b2, c1, h1s, h1f);
        }
    } else {
        for (int st = 0; st < 64; ++st) {
            const half_t* xt; int ldx;
            if (modeB) { xt = X + (size_t)st*1024; ldx = 64*1024; }
            else {
                gemm_ms<<<4*8, 256, 0, stream>>>(
                    ga(obs16 + (size_t)st*512, 64*512, fc1c, 512, 512, fc1_b, X, 1024, 1),
                    Z, Z, 4, 1);
                xt = X; ldx = 1024;
            }
            gemm_ms<<<4*32*2, 256, 0, stream>>>(
                ga(xt, ldx,   wx1c, 1024, 1024, nullptr, preA, 4096, 1),
                ga(h0s, 1024, wh1t, 1024, 1024, nullptr, preB, 4096, 1), Z, 4, 2);
            lstm_cell<<<512, 256, 0, stream>>>(preA, 4096, preB, 4096, b1, c0, h0s, h0f);
            gemm_ms<<<4*32*2, 256, 0, stream>>>(
                ga(h0s, 1024, wx2c, 1024, 1024, nullptr, preA, 4096, 1),
                ga(h1s, 1024, wh2t, 1024, 1024, nullptr, preB, 4096, 1), Z, 4, 2);
            lstm_cell<<<512, 256, 0, stream>>>(preA, 4096, preB, 4096, b2, c1, h1s, h1f);
        }
    }

    // fc2: logit = h1 @ fc2_w^T + fc2_b  -> d_out[0 : 512*1024) as fp32
    gemm_ms<<<4*8, 256, 0, stream>>>(
        ga(h1s, 1024, fc2c, 1024, 1024, fc2_b, out, 1024, 0), Z, Z, 4, 1);
    pack_out<<<2048, 256, 0, stream>>>(h0f, h1f, c0, c1, out);
}